// Round 1
// baseline (554.756 us; speedup 1.0000x reference)
//
#include <hip/hip_runtime.h>
#include <hip/hip_bf16.h>
#include <type_traits>

// Problem constants
constexpr int Bc = 2, Hc = 64, Wc = 128, Cc = 256;
constexpr int HEADS = 8, KPT = 9, HIDDEN = 1024;
constexpr int HD = Cc / HEADS;           // 32
constexpr int NPIX = Hc * Wc;            // 8192
constexpr int Mrows = Bc * NPIX;         // 16384

__device__ __forceinline__ float bf2f(unsigned short u) {
    union { unsigned int i; float f; } c; c.i = ((unsigned int)u) << 16; return c.f;
}
__device__ __forceinline__ unsigned short f2bf(float f) {
    __hip_bfloat16 h = __float2bfloat16(f);
    return *reinterpret_cast<unsigned short*>(&h);
}
__device__ __forceinline__ float gelu_exact(float x) {
    return 0.5f * x * (1.0f + erff(x * 0.70710678118654752f));
}

// ---------------- LayerNorm over C=256, one row per 256-thread block ----------------
__global__ __launch_bounds__(256) void ln_kernel(const float* __restrict__ in,
        const float* __restrict__ g, const float* __restrict__ b,
        float* __restrict__ out) {
    const int r = blockIdx.x;
    const int t = threadIdx.x;
    const size_t base = (size_t)r * Cc;
    float val = in[base + t];
    float s = val, s2 = val * val;
    #pragma unroll
    for (int o = 32; o > 0; o >>= 1) { s += __shfl_down(s, o); s2 += __shfl_down(s2, o); }
    __shared__ float ps[4], ps2[4];
    if ((t & 63) == 0) { ps[t >> 6] = s; ps2[t >> 6] = s2; }
    __syncthreads();
    const float ts  = ps[0] + ps[1] + ps[2] + ps[3];
    const float ts2 = ps2[0] + ps2[1] + ps2[2] + ps2[3];
    const float mean = ts * (1.0f / Cc);
    const float var  = ts2 * (1.0f / Cc) - mean * mean;
    const float rstd = rsqrtf(var + 1e-5f);
    out[base + t] = (val - mean) * rstd * g[t] + b[t];
}

// ---------------- Generic f32-accum tiled GEMM: Out[M,N] = A[M,K] @ W[K,N] + bias ----------------
// BM=BN=64, BK=16, 256 threads, 4x4 micro-tile per thread.
template<typename TA, typename TO, bool GELU, bool RESID>
__global__ __launch_bounds__(256) void gemm_kernel(const TA* __restrict__ A,
        const float* __restrict__ Wt, const float* __restrict__ bias,
        const float* __restrict__ resid, TO* __restrict__ Out,
        int Ndim, int Kdim) {
    const int t = threadIdx.x;
    const int row0 = blockIdx.y * 64;
    const int col0 = blockIdx.x * 64;
    __shared__ float As[16][68];   // +4 pad keeps float4 alignment, breaks bank conflicts
    __shared__ float Ws[16][64];
    float acc[4][4] = {};
    const int tm = (t >> 4) << 2;
    const int tn = (t & 15) << 2;
    const int ar = t >> 2, aq = t & 3;

    for (int k0 = 0; k0 < Kdim; k0 += 16) {
        float a0, a1, a2, a3;
        {
            const size_t aoff = (size_t)(row0 + ar) * Kdim + k0 + aq * 4;
            if constexpr (std::is_same<TA, float>::value) {
                const float4 av = *reinterpret_cast<const float4*>(A + aoff);
                a0 = av.x; a1 = av.y; a2 = av.z; a3 = av.w;
            } else {
                const ushort4 av = *reinterpret_cast<const ushort4*>(A + aoff);
                a0 = bf2f(av.x); a1 = bf2f(av.y); a2 = bf2f(av.z); a3 = bf2f(av.w);
            }
        }
        As[aq * 4 + 0][ar] = a0; As[aq * 4 + 1][ar] = a1;
        As[aq * 4 + 2][ar] = a2; As[aq * 4 + 3][ar] = a3;
        #pragma unroll
        for (int i = 0; i < 4; ++i) {
            const int li = t + i * 256;
            const int kk = li >> 6, n = li & 63;
            const int col = col0 + n;
            Ws[kk][n] = (col < Ndim) ? Wt[(size_t)(k0 + kk) * Ndim + col] : 0.0f;
        }
        __syncthreads();
        #pragma unroll
        for (int kk = 0; kk < 16; ++kk) {
            const float4 av = *reinterpret_cast<const float4*>(&As[kk][tm]);
            const float4 bv = *reinterpret_cast<const float4*>(&Ws[kk][tn]);
            acc[0][0] += av.x * bv.x; acc[0][1] += av.x * bv.y; acc[0][2] += av.x * bv.z; acc[0][3] += av.x * bv.w;
            acc[1][0] += av.y * bv.x; acc[1][1] += av.y * bv.y; acc[1][2] += av.y * bv.z; acc[1][3] += av.y * bv.w;
            acc[2][0] += av.z * bv.x; acc[2][1] += av.z * bv.y; acc[2][2] += av.z * bv.z; acc[2][3] += av.z * bv.w;
            acc[3][0] += av.w * bv.x; acc[3][1] += av.w * bv.y; acc[3][2] += av.w * bv.z; acc[3][3] += av.w * bv.w;
        }
        __syncthreads();
    }
    #pragma unroll
    for (int i = 0; i < 4; ++i) {
        const int row = row0 + tm + i;
        #pragma unroll
        for (int j = 0; j < 4; ++j) {
            const int col = col0 + tn + j;
            if (col < Ndim) {
                float v = acc[i][j] + bias[col];
                if constexpr (GELU) v = gelu_exact(v);
                const size_t oidx = (size_t)row * Ndim + col;
                if constexpr (RESID) v += resid[oidx];
                if constexpr (std::is_same<TO, float>::value) Out[oidx] = v;
                else Out[oidx] = f2bf(v);
            }
        }
    }
}

// ---------------- Deformable sampling + softmax + aggregation ----------------
// One 256-thread block per (b, pixel). Phase 1: 72 threads (head,k) compute bilinear
// corners + attn softmax (attn premultiplied into bilinear weights). Phase 2: thread
// t = head*32+d gathers 9*4 corners from v (channel-last -> coalesced) and writes agg.
__global__ __launch_bounds__(256) void sample_kernel(const float* __restrict__ v,
        const float* __restrict__ offb, const float* __restrict__ attl,
        const float* __restrict__ refp, float* __restrict__ agg) {
    const int m = blockIdx.x;
    const int b = m / NPIX;
    const int pix = m - b * NPIX;
    const int t = threadIdx.x;
    __shared__ int   s_i0[72], s_i1[72], s_i2[72], s_i3[72];
    __shared__ float s_w0[72], s_w1[72], s_w2[72], s_w3[72];
    __shared__ float s_lg[72];
    if (t < 72) {
        const int head = t / 9, k = t - head * 9;
        const float ox = offb[(size_t)m * 144 + head * 18 + k * 2 + 0];
        const float oy = offb[(size_t)m * 144 + head * 18 + k * 2 + 1];
        const float rx = refp[((size_t)pix * KPT + k) * 2 + 0];
        const float ry = refp[((size_t)pix * KPT + k) * 2 + 1];
        const float cx = (rx + ox + 1.0f) * 0.5f * (Wc - 1);
        const float cy = (ry + oy + 1.0f) * 0.5f * (Hc - 1);
        const float fx = floorf(cx), fy = floorf(cy);
        const float wx = cx - fx, wy = cy - fy;
        const int x0 = min(max((int)fx, 0), Wc - 1);
        const int x1 = min(max((int)fx + 1, 0), Wc - 1);
        const int y0 = min(max((int)fy, 0), Hc - 1);
        const int y1 = min(max((int)fy + 1, 0), Hc - 1);
        s_i0[t] = y0 * Wc + x0; s_i1[t] = y0 * Wc + x1;
        s_i2[t] = y1 * Wc + x0; s_i3[t] = y1 * Wc + x1;
        s_w0[t] = (1.0f - wy) * (1.0f - wx); s_w1[t] = (1.0f - wy) * wx;
        s_w2[t] = wy * (1.0f - wx);          s_w3[t] = wy * wx;
        s_lg[t] = attl[(size_t)m * 72 + t];
    }
    __syncthreads();
    if (t < 72) {
        const int head = t / 9;
        float mx = -1e30f;
        #pragma unroll
        for (int k = 0; k < 9; ++k) mx = fmaxf(mx, s_lg[head * 9 + k]);
        float sm = 0.0f;
        #pragma unroll
        for (int k = 0; k < 9; ++k) sm += __expf(s_lg[head * 9 + k] - mx);
        const float a = __expf(s_lg[t] - mx) / sm;
        s_w0[t] *= a; s_w1[t] *= a; s_w2[t] *= a; s_w3[t] *= a;
    }
    __syncthreads();
    const int head = t >> 5, d = t & 31;
    const float* vb = v + (size_t)b * NPIX * Cc + head * HD + d;
    float acc = 0.0f;
    #pragma unroll
    for (int k = 0; k < 9; ++k) {
        const int hk = head * 9 + k;
        acc += vb[(size_t)s_i0[hk] * Cc] * s_w0[hk]
             + vb[(size_t)s_i1[hk] * Cc] * s_w1[hk]
             + vb[(size_t)s_i2[hk] * Cc] * s_w2[hk]
             + vb[(size_t)s_i3[hk] * Cc] * s_w3[hk];
    }
    agg[(size_t)m * Cc + t] = acc;
}

// ---------------- Depthwise 3x3 conv (circular W, zero H) + GELU, bf16 in/out ----------------
// One block per pixel; thread t handles channels [4t, 4t+4).
__global__ __launch_bounds__(256) void dwconv_kernel(const unsigned short* __restrict__ h,
        const float* __restrict__ wdw, const float* __restrict__ bdw,
        unsigned short* __restrict__ h2) {
    const int m = blockIdx.x;
    const int b = m / NPIX;
    const int pix = m - b * NPIX;
    const int y = pix / Wc, x = pix - y * Wc;
    const int t = threadIdx.x;
    const int c0 = t * 4;
    float acc0 = 0.f, acc1 = 0.f, acc2 = 0.f, acc3 = 0.f;
    #pragma unroll
    for (int dy = -1; dy <= 1; ++dy) {
        const int yy = y + dy;
        if (yy < 0 || yy >= Hc) continue;     // zero pad along height
        #pragma unroll
        for (int dx = -1; dx <= 1; ++dx) {
            int xx = x + dx;                   // circular pad along width
            xx = (xx < 0) ? xx + Wc : (xx >= Wc ? xx - Wc : xx);
            const ushort4 hv = *reinterpret_cast<const ushort4*>(
                h + ((size_t)(b * NPIX + yy * Wc + xx)) * HIDDEN + c0);
            const int wj = (dy + 1) * 3 + (dx + 1);
            acc0 += bf2f(hv.x) * wdw[(c0 + 0) * 9 + wj];
            acc1 += bf2f(hv.y) * wdw[(c0 + 1) * 9 + wj];
            acc2 += bf2f(hv.z) * wdw[(c0 + 2) * 9 + wj];
            acc3 += bf2f(hv.w) * wdw[(c0 + 3) * 9 + wj];
        }
    }
    ushort4 o;
    o.x = f2bf(gelu_exact(acc0 + bdw[c0 + 0]));
    o.y = f2bf(gelu_exact(acc1 + bdw[c0 + 1]));
    o.z = f2bf(gelu_exact(acc2 + bdw[c0 + 2]));
    o.w = f2bf(gelu_exact(acc3 + bdw[c0 + 3]));
    *reinterpret_cast<ushort4*>(h2 + (size_t)m * HIDDEN + c0) = o;
}

extern "C" void kernel_launch(void* const* d_in, const int* in_sizes, int n_in,
                              void* d_out, int out_size, void* d_ws, size_t ws_size,
                              hipStream_t stream) {
    const float* x      = (const float*)d_in[0];
    const float* refp   = (const float*)d_in[1];
    const float* ln1_g  = (const float*)d_in[2];
    const float* ln1_b  = (const float*)d_in[3];
    const float* w_v    = (const float*)d_in[4];
    const float* b_v    = (const float*)d_in[5];
    const float* w_off  = (const float*)d_in[6];
    const float* b_off  = (const float*)d_in[7];
    const float* w_attn = (const float*)d_in[8];
    const float* b_attn = (const float*)d_in[9];
    const float* w_out  = (const float*)d_in[10];
    const float* b_out  = (const float*)d_in[11];
    const float* ln2_g  = (const float*)d_in[12];
    const float* ln2_b  = (const float*)d_in[13];
    const float* w1     = (const float*)d_in[14];
    const float* b1     = (const float*)d_in[15];
    const float* w_dw   = (const float*)d_in[16];
    const float* b_dw   = (const float*)d_in[17];
    const float* w2     = (const float*)d_in[18];
    const float* b2     = (const float*)d_in[19];
    float* out = (float*)d_out;

    // Workspace layout (bytes). Lifetimes:
    //   [0,16M):  xn -> agg -> y           (sequential reuse)
    //   [16,32M): v        } dead before h is written
    //   [32,42M): off      }
    //   [42,47M): attn     }
    //   [16,48M): h  (bf16)                (overlaps v/off/attn after they die)
    //   [48,80M): h2 (bf16)
    char* wsb = (char*)d_ws;
    float* xn   = (float*)(wsb);
    float* vbuf = (float*)(wsb + (16ull << 20));
    float* offb = (float*)(wsb + (32ull << 20));
    float* attl = (float*)(wsb + (42ull << 20));
    unsigned short* hbuf  = (unsigned short*)(wsb + (16ull << 20));
    unsigned short* h2buf = (unsigned short*)(wsb + (48ull << 20));

    // 1. LN1
    ln_kernel<<<Mrows, 256, 0, stream>>>(x, ln1_g, ln1_b, xn);
    // 2-4. v / offsets / attn logits GEMMs from xn
    dim3 gv(4, Mrows / 64);   // N=256
    gemm_kernel<float, float, false, false><<<gv, 256, 0, stream>>>(xn, w_v, b_v, nullptr, vbuf, 256, 256);
    dim3 go(3, Mrows / 64);   // N=144
    gemm_kernel<float, float, false, false><<<go, 256, 0, stream>>>(xn, w_off, b_off, nullptr, offb, 144, 256);
    dim3 ga(2, Mrows / 64);   // N=72
    gemm_kernel<float, float, false, false><<<ga, 256, 0, stream>>>(xn, w_attn, b_attn, nullptr, attl, 72, 256);
    // 5. deformable sampling + softmax + aggregation (agg reuses xn storage)
    sample_kernel<<<Mrows, 256, 0, stream>>>(vbuf, offb, attl, refp, xn);
    // 6. x2 = x + agg@w_out + b_out  -> d_out
    gemm_kernel<float, float, false, true><<<gv, 256, 0, stream>>>(xn, w_out, b_out, x, out, 256, 256);
    // 7. LN2 (y reuses xn storage)
    ln_kernel<<<Mrows, 256, 0, stream>>>(out, ln2_g, ln2_b, xn);
    // 8. h = gelu(y@w1 + b1), bf16
    dim3 g1(16, Mrows / 64);  // N=1024
    gemm_kernel<float, unsigned short, true, false><<<g1, 256, 0, stream>>>(xn, w1, b1, nullptr, hbuf, 1024, 256);
    // 9. depthwise conv + gelu
    dwconv_kernel<<<Mrows, 256, 0, stream>>>(hbuf, w_dw, b_dw, h2buf);
    // 10. out = x2 + h2@w2 + b2
    gemm_kernel<unsigned short, float, false, true><<<gv, 256, 0, stream>>>(h2buf, w2, b2, out, out, 256, 1024);
}

// Round 2
// 233.156 us; speedup vs baseline: 2.3793x; 2.3793x over previous
//
#include <hip/hip_runtime.h>
#include <hip/hip_bf16.h>
#include <type_traits>

// Problem constants
constexpr int Bc = 2, Hc = 64, Wc = 128, Cc = 256;
constexpr int HEADS = 8, KPT = 9, HIDDEN = 1024;
constexpr int HD = Cc / HEADS;           // 32
constexpr int NPIX = Hc * Wc;            // 8192
constexpr int Mrows = Bc * NPIX;         // 16384
constexpr int NQKV = 512;                // 256 (v) + 144 (off) + 72 (attn) padded to 512

typedef __attribute__((ext_vector_type(4))) float f32x4;
typedef __attribute__((ext_vector_type(8))) short bf16x8;

__device__ __forceinline__ float bf2f(unsigned short u) {
    union { unsigned int i; float f; } c; c.i = ((unsigned int)u) << 16; return c.f;
}
__device__ __forceinline__ unsigned short f2bf(float f) {
    __hip_bfloat16 h = __float2bfloat16(f);
    return *reinterpret_cast<unsigned short*>(&h);
}
__device__ __forceinline__ float gelu_exact(float x) {
    return 0.5f * x * (1.0f + erff(x * 0.70710678118654752f));
}
__device__ __forceinline__ void gl2lds16(const void* g, void* l) {
    __builtin_amdgcn_global_load_lds(
        (const __attribute__((address_space(1))) unsigned int*)g,
        (__attribute__((address_space(3))) unsigned int*)l, 16, 0, 0);
}

// ---------------- LayerNorm over C=256, one row per 256-thread block ----------------
template<typename TO>
__global__ __launch_bounds__(256) void ln_kernel(const float* __restrict__ in,
        const float* __restrict__ g, const float* __restrict__ b,
        TO* __restrict__ out) {
    const int r = blockIdx.x;
    const int t = threadIdx.x;
    const size_t base = (size_t)r * Cc;
    float val = in[base + t];
    float s = val, s2 = val * val;
    #pragma unroll
    for (int o = 32; o > 0; o >>= 1) { s += __shfl_down(s, o); s2 += __shfl_down(s2, o); }
    __shared__ float ps[4], ps2[4];
    if ((t & 63) == 0) { ps[t >> 6] = s; ps2[t >> 6] = s2; }
    __syncthreads();
    const float ts  = ps[0] + ps[1] + ps[2] + ps[3];
    const float ts2 = ps2[0] + ps2[1] + ps2[2] + ps2[3];
    const float mean = ts * (1.0f / Cc);
    const float var  = ts2 * (1.0f / Cc) - mean * mean;
    const float rstd = rsqrtf(var + 1e-5f);
    const float v = (val - mean) * rstd * g[t] + b[t];
    if constexpr (std::is_same<TO, float>::value) out[base + t] = v;
    else out[base + t] = f2bf(v);
}

// ---------------- Weight prep: f32 [K,N] -> bf16 [N,K] (transposed), QKV fused+padded ----
__global__ __launch_bounds__(256) void prep_weights(
        const float* __restrict__ w_v, const float* __restrict__ b_v,
        const float* __restrict__ w_off, const float* __restrict__ b_off,
        const float* __restrict__ w_attn, const float* __restrict__ b_attn,
        const float* __restrict__ w_out, const float* __restrict__ w1,
        const float* __restrict__ w2,
        unsigned short* __restrict__ qkvT, float* __restrict__ qkvB,
        unsigned short* __restrict__ woutT, unsigned short* __restrict__ w1T,
        unsigned short* __restrict__ w2T) {
    const int blk = blockIdx.x;
    const int t = threadIdx.x;
    if (blk < NQKV) {                      // qkvT row n, K=256
        const int n = blk;
        float val = 0.0f;
        if (n < 256)       val = w_v[t * 256 + n];
        else if (n < 400)  val = w_off[t * 144 + (n - 256)];
        else if (n < 472)  val = w_attn[t * 72 + (n - 400)];
        qkvT[n * 256 + t] = f2bf(val);
        if (t == 0) {
            float bv = 0.0f;
            if (n < 256)      bv = b_v[n];
            else if (n < 400) bv = b_off[n - 256];
            else if (n < 472) bv = b_attn[n - 400];
            qkvB[n] = bv;
        }
    } else if (blk < NQKV + 256) {         // woutT row n, K=256
        const int n = blk - NQKV;
        woutT[n * 256 + t] = f2bf(w_out[t * 256 + n]);
    } else if (blk < NQKV + 256 + 1024) {  // w1T row n, K=256
        const int n = blk - (NQKV + 256);
        w1T[n * 256 + t] = f2bf(w1[t * 1024 + n]);
    } else {                               // w2T row n, K=1024
        const int n = blk - (NQKV + 256 + 1024);
        #pragma unroll
        for (int k = t; k < 1024; k += 256)
            w2T[n * 1024 + k] = f2bf(w2[k * 256 + n]);
    }
}

// ---------------- bf16 MFMA GEMM: Out[M,N] = A[M,K] @ BT[N,K]^T + bias ----------------
// Tile 128 x BN, BK=64, 256 threads (4 waves, 2x2 wave grid), 16x16x32 bf16 MFMA.
// LDS layout: [rows][64] bf16 (128 B / row) with G4 XOR swizzle byte^=((row&7)<<4),
// realized as linear global_load_lds dest + inverse-swizzled global source (rule #21).
template<int BN, bool GELU, bool RESID, typename TO>
__global__ __launch_bounds__(256) void mfma_gemm(
        const unsigned short* __restrict__ A,   // [M,K] bf16
        const unsigned short* __restrict__ BT,  // [N,K] bf16
        const float* __restrict__ bias,         // [N]
        const float* __restrict__ resid,        // [M,N] f32 (if RESID)
        TO* __restrict__ Out,                   // [M,N]
        int N, int K) {
    constexpr int NFR = BN / 32;                // B fragments per wave (128->4, 64->2)
    __shared__ unsigned short As[128 * 64];
    __shared__ unsigned short Bs[BN * 64];
    const int t = threadIdx.x;
    const int w = t >> 6;
    const int l = t & 63;
    const int row0 = blockIdx.y * 128;
    const int col0 = blockIdx.x * BN;
    const int wr = (w >> 1) * 64;               // wave row offset in tile
    const int wc = (w & 1) * (BN / 2);          // wave col offset in tile

    // staging geometry: chunk = 8 rows x 64 cols (1024 B); lane l -> row c*8+l/8,
    // 16B slot (l%8); source slot is XOR-swizzled so LDS holds swizzled layout.
    const int srow = l >> 3;
    const int selem = ((l & 7) ^ srow) * 8;     // element offset of this lane's 16B

    f32x4 acc[4][NFR] = {};

    for (int k0 = 0; k0 < K; k0 += 64) {
        #pragma unroll
        for (int i = 0; i < 4; ++i) {           // A tile: 16 chunks, 4 per wave
            const int c = w + i * 4;
            const int row = c * 8 + srow;
            gl2lds16(A + (size_t)(row0 + row) * K + k0 + selem, As + c * 512);
        }
        #pragma unroll
        for (int i = 0; i < NFR; ++i) {         // B tile: BN/8 chunks
            const int c = w + i * 4;
            const int row = c * 8 + srow;
            gl2lds16(BT + (size_t)(col0 + row) * K + k0 + selem, Bs + c * 512);
        }
        asm volatile("s_waitcnt vmcnt(0)" ::: "memory");
        __syncthreads();
        #pragma unroll
        for (int ks = 0; ks < 2; ++ks) {
            const int kb = ks * 64 + (l >> 4) * 16;   // byte offset within 128B row
            bf16x8 af[4], bfr[NFR];
            #pragma unroll
            for (int mi = 0; mi < 4; ++mi) {
                const int row = wr + mi * 16 + (l & 15);
                af[mi] = *(const bf16x8*)((const char*)As + row * 128 + (kb ^ ((row & 7) << 4)));
            }
            #pragma unroll
            for (int ni = 0; ni < NFR; ++ni) {
                const int row = wc + ni * 16 + (l & 15);
                bfr[ni] = *(const bf16x8*)((const char*)Bs + row * 128 + (kb ^ ((row & 7) << 4)));
            }
            #pragma unroll
            for (int mi = 0; mi < 4; ++mi)
                #pragma unroll
                for (int ni = 0; ni < NFR; ++ni)
                    acc[mi][ni] = __builtin_amdgcn_mfma_f32_16x16x32_bf16(
                        af[mi], bfr[ni], acc[mi][ni], 0, 0, 0);
        }
        __syncthreads();
    }

    // epilogue: C/D layout col=l&15, row=(l>>4)*4+reg (guide §3, m89-verified)
    const int lrow = (l >> 4) * 4;
    const int lcol = l & 15;
    #pragma unroll
    for (int ni = 0; ni < NFR; ++ni) {
        const int col = col0 + wc + ni * 16 + lcol;
        const float bb = bias[col];
        #pragma unroll
        for (int mi = 0; mi < 4; ++mi) {
            #pragma unroll
            for (int r = 0; r < 4; ++r) {
                const int row = row0 + wr + mi * 16 + lrow + r;
                float v = acc[mi][ni][r] + bb;
                if constexpr (GELU) v = gelu_exact(v);
                const size_t o = (size_t)row * N + col;
                if constexpr (RESID) v += resid[o];
                if constexpr (std::is_same<TO, float>::value) Out[o] = v;
                else Out[o] = f2bf(v);
            }
        }
    }
}

// ---------------- Deformable sampling + softmax + aggregation (bf16 in/out) ----------------
// F = fused QKV buffer [M, 512]: cols 0-255 v, 256-399 offsets, 400-471 attn logits.
__global__ __launch_bounds__(256) void sample_kernel(const unsigned short* __restrict__ F,
        const float* __restrict__ refp, unsigned short* __restrict__ agg) {
    const int m = blockIdx.x;
    const int b = m / NPIX;
    const int pix = m - b * NPIX;
    const int t = threadIdx.x;
    __shared__ int   s_i0[72], s_i1[72], s_i2[72], s_i3[72];
    __shared__ float s_w0[72], s_w1[72], s_w2[72], s_w3[72];
    __shared__ float s_lg[72];
    if (t < 72) {
        const int head = t / 9, k = t - head * 9;
        const size_t fb = (size_t)m * NQKV;
        const float ox = bf2f(F[fb + 256 + head * 18 + k * 2 + 0]);
        const float oy = bf2f(F[fb + 256 + head * 18 + k * 2 + 1]);
        const float rx = refp[((size_t)pix * KPT + k) * 2 + 0];
        const float ry = refp[((size_t)pix * KPT + k) * 2 + 1];
        const float cx = (rx + ox + 1.0f) * 0.5f * (Wc - 1);
        const float cy = (ry + oy + 1.0f) * 0.5f * (Hc - 1);
        const float fx = floorf(cx), fy = floorf(cy);
        const float wx = cx - fx, wy = cy - fy;
        const int x0 = min(max((int)fx, 0), Wc - 1);
        const int x1 = min(max((int)fx + 1, 0), Wc - 1);
        const int y0 = min(max((int)fy, 0), Hc - 1);
        const int y1 = min(max((int)fy + 1, 0), Hc - 1);
        s_i0[t] = y0 * Wc + x0; s_i1[t] = y0 * Wc + x1;
        s_i2[t] = y1 * Wc + x0; s_i3[t] = y1 * Wc + x1;
        s_w0[t] = (1.0f - wy) * (1.0f - wx); s_w1[t] = (1.0f - wy) * wx;
        s_w2[t] = wy * (1.0f - wx);          s_w3[t] = wy * wx;
        s_lg[t] = bf2f(F[fb + 400 + t]);
    }
    __syncthreads();
    if (t < 72) {
        const int head = t / 9;
        float mx = -1e30f;
        #pragma unroll
        for (int k = 0; k < 9; ++k) mx = fmaxf(mx, s_lg[head * 9 + k]);
        float sm = 0.0f;
        #pragma unroll
        for (int k = 0; k < 9; ++k) sm += __expf(s_lg[head * 9 + k] - mx);
        const float a = __expf(s_lg[t] - mx) / sm;
        s_w0[t] *= a; s_w1[t] *= a; s_w2[t] *= a; s_w3[t] *= a;
    }
    __syncthreads();
    const int head = t >> 5, d = t & 31;
    const unsigned short* vb = F + (size_t)b * NPIX * NQKV + head * HD + d;
    float acc = 0.0f;
    #pragma unroll
    for (int k = 0; k < 9; ++k) {
        const int hk = head * 9 + k;
        acc += bf2f(vb[(size_t)s_i0[hk] * NQKV]) * s_w0[hk]
             + bf2f(vb[(size_t)s_i1[hk] * NQKV]) * s_w1[hk]
             + bf2f(vb[(size_t)s_i2[hk] * NQKV]) * s_w2[hk]
             + bf2f(vb[(size_t)s_i3[hk] * NQKV]) * s_w3[hk];
    }
    agg[(size_t)m * Cc + t] = f2bf(acc);
}

// ---------------- Depthwise 3x3 conv (circular W, zero H) + GELU, bf16 in/out ----------------
__global__ __launch_bounds__(256) void dwconv_kernel(const unsigned short* __restrict__ h,
        const float* __restrict__ wdw, const float* __restrict__ bdw,
        unsigned short* __restrict__ h2) {
    const int m = blockIdx.x;
    const int b = m / NPIX;
    const int pix = m - b * NPIX;
    const int y = pix / Wc, x = pix - y * Wc;
    const int t = threadIdx.x;
    const int c0 = t * 4;
    float acc0 = 0.f, acc1 = 0.f, acc2 = 0.f, acc3 = 0.f;
    #pragma unroll
    for (int dy = -1; dy <= 1; ++dy) {
        const int yy = y + dy;
        if (yy < 0 || yy >= Hc) continue;     // zero pad along height
        #pragma unroll
        for (int dx = -1; dx <= 1; ++dx) {
            int xx = x + dx;                   // circular pad along width
            xx = (xx < 0) ? xx + Wc : (xx >= Wc ? xx - Wc : xx);
            const ushort4 hv = *reinterpret_cast<const ushort4*>(
                h + ((size_t)(b * NPIX + yy * Wc + xx)) * HIDDEN + c0);
            const int wj = (dy + 1) * 3 + (dx + 1);
            acc0 += bf2f(hv.x) * wdw[(c0 + 0) * 9 + wj];
            acc1 += bf2f(hv.y) * wdw[(c0 + 1) * 9 + wj];
            acc2 += bf2f(hv.z) * wdw[(c0 + 2) * 9 + wj];
            acc3 += bf2f(hv.w) * wdw[(c0 + 3) * 9 + wj];
        }
    }
    ushort4 o;
    o.x = f2bf(gelu_exact(acc0 + bdw[c0 + 0]));
    o.y = f2bf(gelu_exact(acc1 + bdw[c0 + 1]));
    o.z = f2bf(gelu_exact(acc2 + bdw[c0 + 2]));
    o.w = f2bf(gelu_exact(acc3 + bdw[c0 + 3]));
    *reinterpret_cast<ushort4*>(h2 + (size_t)m * HIDDEN + c0) = o;
}

extern "C" void kernel_launch(void* const* d_in, const int* in_sizes, int n_in,
                              void* d_out, int out_size, void* d_ws, size_t ws_size,
                              hipStream_t stream) {
    const float* x      = (const float*)d_in[0];
    const float* refp   = (const float*)d_in[1];
    const float* ln1_g  = (const float*)d_in[2];
    const float* ln1_b  = (const float*)d_in[3];
    const float* w_v    = (const float*)d_in[4];
    const float* b_v    = (const float*)d_in[5];
    const float* w_off  = (const float*)d_in[6];
    const float* b_off  = (const float*)d_in[7];
    const float* w_attn = (const float*)d_in[8];
    const float* b_attn = (const float*)d_in[9];
    const float* w_out  = (const float*)d_in[10];
    const float* b_out  = (const float*)d_in[11];
    const float* ln2_g  = (const float*)d_in[12];
    const float* ln2_b  = (const float*)d_in[13];
    const float* w1     = (const float*)d_in[14];
    const float* b1     = (const float*)d_in[15];
    const float* w_dw   = (const float*)d_in[16];
    const float* b_dw   = (const float*)d_in[17];
    const float* w2     = (const float*)d_in[18];
    const float* b2     = (const float*)d_in[19];
    float* out = (float*)d_out;

    // Workspace layout (bytes); lifetimes make the overlaps safe:
    //  [0,  8M): xn -> agg -> y          (bf16 [M,256], sequential reuse)
    //  [8, 24M): F fused qkv (bf16 [M,512]) — dead after sample_kernel
    //  [8, 40M): h (bf16 [M,1024])       — written after F is dead
    //  [40,72M): h2 (bf16 [M,1024])
    //  [72M,..): transposed bf16 weights + fused qkv bias
    char* wsb = (char*)d_ws;
    unsigned short* xnR = (unsigned short*)(wsb);
    unsigned short* F   = (unsigned short*)(wsb + (8ull  << 20));
    unsigned short* h   = (unsigned short*)(wsb + (8ull  << 20));
    unsigned short* h2  = (unsigned short*)(wsb + (40ull << 20));
    size_t woff = 72ull << 20;
    unsigned short* qkvT = (unsigned short*)(wsb + woff); woff += (size_t)NQKV * 256 * 2;
    unsigned short* woutT= (unsigned short*)(wsb + woff); woff += 256 * 256 * 2;
    unsigned short* w1T  = (unsigned short*)(wsb + woff); woff += 1024 * 256 * 2;
    unsigned short* w2T  = (unsigned short*)(wsb + woff); woff += 256 * 1024 * 2;
    float*          qkvB = (float*)(wsb + woff);

    // 0. weight transpose/convert (independent of activations)
    prep_weights<<<NQKV + 256 + 1024 + 256, 256, 0, stream>>>(
        w_v, b_v, w_off, b_off, w_attn, b_attn, w_out, w1, w2,
        qkvT, qkvB, woutT, w1T, w2T);
    // 1. LN1 -> xn (bf16)
    ln_kernel<unsigned short><<<Mrows, 256, 0, stream>>>(x, ln1_g, ln1_b, xnR);
    // 2. fused QKV GEMM: F = xn @ [w_v|w_off|w_attn] + bias  (bf16 out)
    mfma_gemm<128, false, false, unsigned short><<<dim3(NQKV / 128, Mrows / 128), 256, 0, stream>>>(
        xnR, qkvT, qkvB, nullptr, F, NQKV, 256);
    // 3. deformable sampling + softmax + aggregation -> agg (reuses xn region)
    sample_kernel<<<Mrows, 256, 0, stream>>>(F, refp, xnR);
    // 4. x2 = x + agg @ w_out + b_out -> d_out (f32)
    mfma_gemm<64, false, true, float><<<dim3(256 / 64, Mrows / 128), 256, 0, stream>>>(
        xnR, woutT, b_out, x, out, 256, 256);
    // 5. LN2 -> y (bf16, reuses xn region)
    ln_kernel<unsigned short><<<Mrows, 256, 0, stream>>>(out, ln2_g, ln2_b, xnR);
    // 6. h = gelu(y @ w1 + b1) (bf16)
    mfma_gemm<128, true, false, unsigned short><<<dim3(1024 / 128, Mrows / 128), 256, 0, stream>>>(
        xnR, w1T, b1, nullptr, h, 1024, 256);
    // 7. depthwise conv + gelu -> h2 (bf16)
    dwconv_kernel<<<Mrows, 256, 0, stream>>>(h, w_dw, b_dw, h2);
    // 8. out = x2 + h2 @ w2 + b2 (f32, in-place residual)
    mfma_gemm<64, false, true, float><<<dim3(256 / 64, Mrows / 128), 256, 0, stream>>>(
        h2, w2T, b2, out, out, 256, 1024);
}

// Round 3
// 199.136 us; speedup vs baseline: 2.7858x; 1.1708x over previous
//
#include <hip/hip_runtime.h>
#include <hip/hip_bf16.h>
#include <type_traits>

// Problem constants
constexpr int Bc = 2, Hc = 64, Wc = 128, Cc = 256;
constexpr int HEADS = 8, KPT = 9, HIDDEN = 1024;
constexpr int HD = Cc / HEADS;           // 32
constexpr int NPIX = Hc * Wc;            // 8192
constexpr int Mrows = Bc * NPIX;         // 16384
constexpr int NQKV = 512;                // 256 (v) + 144 (off) + 72 (attn) padded to 512

typedef __attribute__((ext_vector_type(4))) float f32x4;
typedef __attribute__((ext_vector_type(8))) short bf16x8;

__device__ __forceinline__ float bf2f(unsigned short u) {
    union { unsigned int i; float f; } c; c.i = ((unsigned int)u) << 16; return c.f;
}
__device__ __forceinline__ unsigned short f2bf(float f) {
    __hip_bfloat16 h = __float2bfloat16(f);
    return *reinterpret_cast<unsigned short*>(&h);
}
__device__ __forceinline__ float gelu_exact(float x) {
    return 0.5f * x * (1.0f + erff(x * 0.70710678118654752f));
}
__device__ __forceinline__ void gl2lds16(const void* g, void* l) {
    __builtin_amdgcn_global_load_lds(
        (const __attribute__((address_space(1))) unsigned int*)g,
        (__attribute__((address_space(3))) unsigned int*)l, 16, 0, 0);
}

// ---------------- LayerNorm over C=256, one row per 256-thread block ----------------
template<typename TO>
__global__ __launch_bounds__(256) void ln_kernel(const float* __restrict__ in,
        const float* __restrict__ g, const float* __restrict__ b,
        TO* __restrict__ out) {
    const int r = blockIdx.x;
    const int t = threadIdx.x;
    const size_t base = (size_t)r * Cc;
    float val = in[base + t];
    float s = val, s2 = val * val;
    #pragma unroll
    for (int o = 32; o > 0; o >>= 1) { s += __shfl_down(s, o); s2 += __shfl_down(s2, o); }
    __shared__ float ps[4], ps2[4];
    if ((t & 63) == 0) { ps[t >> 6] = s; ps2[t >> 6] = s2; }
    __syncthreads();
    const float ts  = ps[0] + ps[1] + ps[2] + ps[3];
    const float ts2 = ps2[0] + ps2[1] + ps2[2] + ps2[3];
    const float mean = ts * (1.0f / Cc);
    const float var  = ts2 * (1.0f / Cc) - mean * mean;
    const float rstd = rsqrtf(var + 1e-5f);
    const float v = (val - mean) * rstd * g[t] + b[t];
    if constexpr (std::is_same<TO, float>::value) out[base + t] = v;
    else out[base + t] = f2bf(v);
}

// ---------------- Weight prep: f32 [K,N] -> bf16 [N,K] (transposed), QKV fused+padded ----
// Also transposes depthwise weights [1024][9] -> [9][1024] f32 for coalesced loads.
__global__ __launch_bounds__(256) void prep_weights(
        const float* __restrict__ w_v, const float* __restrict__ b_v,
        const float* __restrict__ w_off, const float* __restrict__ b_off,
        const float* __restrict__ w_attn, const float* __restrict__ b_attn,
        const float* __restrict__ w_out, const float* __restrict__ w1,
        const float* __restrict__ w2, const float* __restrict__ w_dw,
        unsigned short* __restrict__ qkvT, float* __restrict__ qkvB,
        unsigned short* __restrict__ woutT, unsigned short* __restrict__ w1T,
        unsigned short* __restrict__ w2T, float* __restrict__ wdwT) {
    const int blk = blockIdx.x;
    const int t = threadIdx.x;
    if (blk < NQKV) {                      // qkvT row n, K=256
        const int n = blk;
        float val = 0.0f;
        if (n < 256)       val = w_v[t * 256 + n];
        else if (n < 400)  val = w_off[t * 144 + (n - 256)];
        else if (n < 472)  val = w_attn[t * 72 + (n - 400)];
        qkvT[n * 256 + t] = f2bf(val);
        if (t == 0) {
            float bv = 0.0f;
            if (n < 256)      bv = b_v[n];
            else if (n < 400) bv = b_off[n - 256];
            else if (n < 472) bv = b_attn[n - 400];
            qkvB[n] = bv;
        }
    } else if (blk < NQKV + 256) {         // woutT row n, K=256
        const int n = blk - NQKV;
        woutT[n * 256 + t] = f2bf(w_out[t * 256 + n]);
    } else if (blk < NQKV + 256 + 1024) {  // w1T row n, K=256
        const int n = blk - (NQKV + 256);
        w1T[n * 256 + t] = f2bf(w1[t * 1024 + n]);
    } else if (blk < NQKV + 256 + 1024 + 256) { // w2T row n, K=1024
        const int n = blk - (NQKV + 256 + 1024);
        #pragma unroll
        for (int k = t; k < 1024; k += 256)
            w2T[n * 1024 + k] = f2bf(w2[k * 256 + n]);
    } else {                               // wdwT row j (9 rows)
        const int j = blk - (NQKV + 256 + 1024 + 256);
        #pragma unroll
        for (int c = t; c < HIDDEN; c += 256)
            wdwT[j * HIDDEN + c] = w_dw[c * 9 + j];
    }
}

// ---------------- bf16 MFMA GEMM: Out[M,N] = A[M,K] @ BT[N,K]^T + bias ----------------
// Tile 128 x BN, BK=64, 256 threads (4 waves, 2x2 wave grid), 16x16x32 bf16 MFMA.
// LDS layout: [rows][64] bf16 (128 B / row) with G4 XOR swizzle byte^=((row&7)<<4),
// realized as linear global_load_lds dest + inverse-swizzled global source (rule #21).
template<int BN, bool GELU, bool RESID, typename TO>
__global__ __launch_bounds__(256) void mfma_gemm(
        const unsigned short* __restrict__ A,   // [M,K] bf16
        const unsigned short* __restrict__ BT,  // [N,K] bf16
        const float* __restrict__ bias,         // [N]
        const float* __restrict__ resid,        // [M,N] f32 (if RESID)
        TO* __restrict__ Out,                   // [M,N]
        int N, int K) {
    constexpr int NFR = BN / 32;                // B fragments per wave (128->4, 64->2)
    __shared__ unsigned short As[128 * 64];
    __shared__ unsigned short Bs[BN * 64];
    const int t = threadIdx.x;
    const int w = t >> 6;
    const int l = t & 63;
    const int row0 = blockIdx.y * 128;
    const int col0 = blockIdx.x * BN;
    const int wr = (w >> 1) * 64;               // wave row offset in tile
    const int wc = (w & 1) * (BN / 2);          // wave col offset in tile

    // staging geometry: chunk = 8 rows x 64 cols (1024 B); lane l -> row c*8+l/8,
    // 16B slot (l%8); source slot is XOR-swizzled so LDS holds swizzled layout.
    const int srow = l >> 3;
    const int selem = ((l & 7) ^ srow) * 8;     // element offset of this lane's 16B

    f32x4 acc[4][NFR] = {};

    for (int k0 = 0; k0 < K; k0 += 64) {
        #pragma unroll
        for (int i = 0; i < 4; ++i) {           // A tile: 16 chunks, 4 per wave
            const int c = w + i * 4;
            const int row = c * 8 + srow;
            gl2lds16(A + (size_t)(row0 + row) * K + k0 + selem, As + c * 512);
        }
        #pragma unroll
        for (int i = 0; i < NFR; ++i) {         // B tile: BN/8 chunks
            const int c = w + i * 4;
            const int row = c * 8 + srow;
            gl2lds16(BT + (size_t)(col0 + row) * K + k0 + selem, Bs + c * 512);
        }
        asm volatile("s_waitcnt vmcnt(0)" ::: "memory");
        __syncthreads();
        #pragma unroll
        for (int ks = 0; ks < 2; ++ks) {
            const int kb = ks * 64 + (l >> 4) * 16;   // byte offset within 128B row
            bf16x8 af[4], bfr[NFR];
            #pragma unroll
            for (int mi = 0; mi < 4; ++mi) {
                const int row = wr + mi * 16 + (l & 15);
                af[mi] = *(const bf16x8*)((const char*)As + row * 128 + (kb ^ ((row & 7) << 4)));
            }
            #pragma unroll
            for (int ni = 0; ni < NFR; ++ni) {
                const int row = wc + ni * 16 + (l & 15);
                bfr[ni] = *(const bf16x8*)((const char*)Bs + row * 128 + (kb ^ ((row & 7) << 4)));
            }
            #pragma unroll
            for (int mi = 0; mi < 4; ++mi)
                #pragma unroll
                for (int ni = 0; ni < NFR; ++ni)
                    acc[mi][ni] = __builtin_amdgcn_mfma_f32_16x16x32_bf16(
                        af[mi], bfr[ni], acc[mi][ni], 0, 0, 0);
        }
        __syncthreads();
    }

    // epilogue: C/D layout col=l&15, row=(l>>4)*4+reg (guide §3, m89-verified)
    const int lrow = (l >> 4) * 4;
    const int lcol = l & 15;
    #pragma unroll
    for (int ni = 0; ni < NFR; ++ni) {
        const int col = col0 + wc + ni * 16 + lcol;
        const float bb = bias[col];
        #pragma unroll
        for (int mi = 0; mi < 4; ++mi) {
            #pragma unroll
            for (int r = 0; r < 4; ++r) {
                const int row = row0 + wr + mi * 16 + lrow + r;
                float v = acc[mi][ni][r] + bb;
                if constexpr (GELU) v = gelu_exact(v);
                const size_t o = (size_t)row * N + col;
                if constexpr (RESID) v += resid[o];
                if constexpr (std::is_same<TO, float>::value) Out[o] = v;
                else Out[o] = f2bf(v);
            }
        }
    }
}

// ---------------- Deformable sampling + softmax + aggregation (bf16 in/out) ----------------
// F = fused QKV buffer [M, 512]: cols 0-255 v, 256-399 offsets, 400-471 attn logits.
__global__ __launch_bounds__(256) void sample_kernel(const unsigned short* __restrict__ F,
        const float* __restrict__ refp, unsigned short* __restrict__ agg) {
    const int m = blockIdx.x;
    const int b = m / NPIX;
    const int pix = m - b * NPIX;
    const int t = threadIdx.x;
    __shared__ int   s_i0[72], s_i1[72], s_i2[72], s_i3[72];
    __shared__ float s_w0[72], s_w1[72], s_w2[72], s_w3[72];
    __shared__ float s_lg[72];
    if (t < 72) {
        const int head = t / 9, k = t - head * 9;
        const size_t fb = (size_t)m * NQKV;
        const float ox = bf2f(F[fb + 256 + head * 18 + k * 2 + 0]);
        const float oy = bf2f(F[fb + 256 + head * 18 + k * 2 + 1]);
        const float rx = refp[((size_t)pix * KPT + k) * 2 + 0];
        const float ry = refp[((size_t)pix * KPT + k) * 2 + 1];
        const float cx = (rx + ox + 1.0f) * 0.5f * (Wc - 1);
        const float cy = (ry + oy + 1.0f) * 0.5f * (Hc - 1);
        const float fx = floorf(cx), fy = floorf(cy);
        const float wx = cx - fx, wy = cy - fy;
        const int x0 = min(max((int)fx, 0), Wc - 1);
        const int x1 = min(max((int)fx + 1, 0), Wc - 1);
        const int y0 = min(max((int)fy, 0), Hc - 1);
        const int y1 = min(max((int)fy + 1, 0), Hc - 1);
        s_i0[t] = y0 * Wc + x0; s_i1[t] = y0 * Wc + x1;
        s_i2[t] = y1 * Wc + x0; s_i3[t] = y1 * Wc + x1;
        s_w0[t] = (1.0f - wy) * (1.0f - wx); s_w1[t] = (1.0f - wy) * wx;
        s_w2[t] = wy * (1.0f - wx);          s_w3[t] = wy * wx;
        s_lg[t] = bf2f(F[fb + 400 + t]);
    }
    __syncthreads();
    if (t < 72) {
        const int head = t / 9;
        float mx = -1e30f;
        #pragma unroll
        for (int k = 0; k < 9; ++k) mx = fmaxf(mx, s_lg[head * 9 + k]);
        float sm = 0.0f;
        #pragma unroll
        for (int k = 0; k < 9; ++k) sm += __expf(s_lg[head * 9 + k] - mx);
        const float a = __expf(s_lg[t] - mx) / sm;
        s_w0[t] *= a; s_w1[t] *= a; s_w2[t] *= a; s_w3[t] *= a;
    }
    __syncthreads();
    const int head = t >> 5, d = t & 31;
    const unsigned short* vb = F + (size_t)b * NPIX * NQKV + head * HD + d;
    float acc = 0.0f;
    #pragma unroll
    for (int k = 0; k < 9; ++k) {
        const int hk = head * 9 + k;
        acc += bf2f(vb[(size_t)s_i0[hk] * NQKV]) * s_w0[hk]
             + bf2f(vb[(size_t)s_i1[hk] * NQKV]) * s_w1[hk]
             + bf2f(vb[(size_t)s_i2[hk] * NQKV]) * s_w2[hk]
             + bf2f(vb[(size_t)s_i3[hk] * NQKV]) * s_w3[hk];
    }
    agg[(size_t)m * Cc + t] = f2bf(acc);
}

// ---------------- Depthwise 3x3 conv (circular W, zero H) + GELU, bf16 in/out ----------------
// Weights pre-transposed to [9][1024] so per-thread float4 loads are coalesced and
// hoisted into registers. XCD-chunked block swizzle keeps neighbor rows in one L2.
__global__ __launch_bounds__(256) void dwconv_kernel(const unsigned short* __restrict__ h,
        const float* __restrict__ wdwT, const float* __restrict__ bdw,
        unsigned short* __restrict__ h2) {
    const int bid = blockIdx.x;
    const int m = (bid & 7) * (Mrows / 8) + (bid >> 3);   // XCD-chunked swizzle (16384 % 8 == 0)
    const int b = m / NPIX;
    const int pix = m - b * NPIX;
    const int y = pix / Wc, x = pix - y * Wc;
    const int t = threadIdx.x;
    const int c0 = t * 4;

    float wreg[9][4];
    #pragma unroll
    for (int j = 0; j < 9; ++j) {
        const float4 wv = *reinterpret_cast<const float4*>(wdwT + j * HIDDEN + c0);
        wreg[j][0] = wv.x; wreg[j][1] = wv.y; wreg[j][2] = wv.z; wreg[j][3] = wv.w;
    }

    float acc0 = 0.f, acc1 = 0.f, acc2 = 0.f, acc3 = 0.f;
    #pragma unroll
    for (int dy = -1; dy <= 1; ++dy) {
        const int yy = y + dy;
        if (yy < 0 || yy >= Hc) continue;     // zero pad along height (block-uniform branch)
        #pragma unroll
        for (int dx = -1; dx <= 1; ++dx) {
            int xx = x + dx;                   // circular pad along width
            xx = (xx < 0) ? xx + Wc : (xx >= Wc ? xx - Wc : xx);
            const ushort4 hv = *reinterpret_cast<const ushort4*>(
                h + ((size_t)(b * NPIX + yy * Wc + xx)) * HIDDEN + c0);
            const int wj = (dy + 1) * 3 + (dx + 1);
            acc0 += bf2f(hv.x) * wreg[wj][0];
            acc1 += bf2f(hv.y) * wreg[wj][1];
            acc2 += bf2f(hv.z) * wreg[wj][2];
            acc3 += bf2f(hv.w) * wreg[wj][3];
        }
    }
    ushort4 o;
    o.x = f2bf(gelu_exact(acc0 + bdw[c0 + 0]));
    o.y = f2bf(gelu_exact(acc1 + bdw[c0 + 1]));
    o.z = f2bf(gelu_exact(acc2 + bdw[c0 + 2]));
    o.w = f2bf(gelu_exact(acc3 + bdw[c0 + 3]));
    *reinterpret_cast<ushort4*>(h2 + (size_t)m * HIDDEN + c0) = o;
}

extern "C" void kernel_launch(void* const* d_in, const int* in_sizes, int n_in,
                              void* d_out, int out_size, void* d_ws, size_t ws_size,
                              hipStream_t stream) {
    const float* x      = (const float*)d_in[0];
    const float* refp   = (const float*)d_in[1];
    const float* ln1_g  = (const float*)d_in[2];
    const float* ln1_b  = (const float*)d_in[3];
    const float* w_v    = (const float*)d_in[4];
    const float* b_v    = (const float*)d_in[5];
    const float* w_off  = (const float*)d_in[6];
    const float* b_off  = (const float*)d_in[7];
    const float* w_attn = (const float*)d_in[8];
    const float* b_attn = (const float*)d_in[9];
    const float* w_out  = (const float*)d_in[10];
    const float* b_out  = (const float*)d_in[11];
    const float* ln2_g  = (const float*)d_in[12];
    const float* ln2_b  = (const float*)d_in[13];
    const float* w1     = (const float*)d_in[14];
    const float* b1     = (const float*)d_in[15];
    const float* w_dw   = (const float*)d_in[16];
    const float* b_dw   = (const float*)d_in[17];
    const float* w2     = (const float*)d_in[18];
    const float* b2     = (const float*)d_in[19];
    float* out = (float*)d_out;

    // Workspace layout (bytes); lifetimes make the overlaps safe:
    //  [0,  8M): xn -> agg -> y          (bf16 [M,256], sequential reuse)
    //  [8, 24M): F fused qkv (bf16 [M,512]) — dead after sample_kernel
    //  [8, 40M): h (bf16 [M,1024])       — written after F is dead
    //  [40,72M): h2 (bf16 [M,1024])
    //  [72M,..): transposed bf16 weights + wdwT + fused qkv bias
    char* wsb = (char*)d_ws;
    unsigned short* xnR = (unsigned short*)(wsb);
    unsigned short* F   = (unsigned short*)(wsb + (8ull  << 20));
    unsigned short* h   = (unsigned short*)(wsb + (8ull  << 20));
    unsigned short* h2  = (unsigned short*)(wsb + (40ull << 20));
    size_t woff = 72ull << 20;
    unsigned short* qkvT = (unsigned short*)(wsb + woff); woff += (size_t)NQKV * 256 * 2;
    unsigned short* woutT= (unsigned short*)(wsb + woff); woff += 256 * 256 * 2;
    unsigned short* w1T  = (unsigned short*)(wsb + woff); woff += 1024 * 256 * 2;
    unsigned short* w2T  = (unsigned short*)(wsb + woff); woff += 256 * 1024 * 2;
    float*          wdwT = (float*)(wsb + woff);          woff += 9 * 1024 * 4;
    float*          qkvB = (float*)(wsb + woff);

    // 0. weight transpose/convert (independent of activations)
    prep_weights<<<NQKV + 256 + 1024 + 256 + 9, 256, 0, stream>>>(
        w_v, b_v, w_off, b_off, w_attn, b_attn, w_out, w1, w2, w_dw,
        qkvT, qkvB, woutT, w1T, w2T, wdwT);
    // 1. LN1 -> xn (bf16)
    ln_kernel<unsigned short><<<Mrows, 256, 0, stream>>>(x, ln1_g, ln1_b, xnR);
    // 2. fused QKV GEMM: F = xn @ [w_v|w_off|w_attn] + bias  (bf16 out)
    mfma_gemm<128, false, false, unsigned short><<<dim3(NQKV / 128, Mrows / 128), 256, 0, stream>>>(
        xnR, qkvT, qkvB, nullptr, F, NQKV, 256);
    // 3. deformable sampling + softmax + aggregation -> agg (reuses xn region)
    sample_kernel<<<Mrows, 256, 0, stream>>>(F, refp, xnR);
    // 4. x2 = x + agg @ w_out + b_out -> d_out (f32)
    mfma_gemm<64, false, true, float><<<dim3(256 / 64, Mrows / 128), 256, 0, stream>>>(
        xnR, woutT, b_out, x, out, 256, 256);
    // 5. LN2 -> y (bf16, reuses xn region)
    ln_kernel<unsigned short><<<Mrows, 256, 0, stream>>>(out, ln2_g, ln2_b, xnR);
    // 6. h = gelu(y @ w1 + b1) (bf16)
    mfma_gemm<128, true, false, unsigned short><<<dim3(1024 / 128, Mrows / 128), 256, 0, stream>>>(
        xnR, w1T, b1, nullptr, h, 1024, 256);
    // 7. depthwise conv + gelu -> h2 (bf16)
    dwconv_kernel<<<Mrows, 256, 0, stream>>>(h, wdwT, b_dw, h2);
    // 8. out = x2 + h2 @ w2 + b2 (f32, in-place residual)
    mfma_gemm<64, false, true, float><<<dim3(256 / 64, Mrows / 128), 256, 0, stream>>>(
        h2, w2T, b2, out, out, 256, 1024);
}

// Round 4
// 169.636 us; speedup vs baseline: 3.2703x; 1.1739x over previous
//
#include <hip/hip_runtime.h>
#include <hip/hip_bf16.h>
#include <type_traits>

// Problem constants
constexpr int Bc = 2, Hc = 64, Wc = 128, Cc = 256;
constexpr int HEADS = 8, KPT = 9, HIDDEN = 1024;
constexpr int HD = Cc / HEADS;           // 32
constexpr int NPIX = Hc * Wc;            // 8192
constexpr int Mrows = Bc * NPIX;         // 16384
constexpr int NQKV = 512;                // 256 (v) + 144 (off) + 72 (attn) padded to 512

typedef __attribute__((ext_vector_type(4))) float f32x4;
typedef __attribute__((ext_vector_type(8))) short bf16x8;

__device__ __forceinline__ float bf2f(unsigned short u) {
    union { unsigned int i; float f; } c; c.i = ((unsigned int)u) << 16; return c.f;
}
__device__ __forceinline__ unsigned short f2bf(float f) {
    __hip_bfloat16 h = __float2bfloat16(f);
    return *reinterpret_cast<unsigned short*>(&h);
}
__device__ __forceinline__ float gelu_exact(float x) {
    return 0.5f * x * (1.0f + erff(x * 0.70710678118654752f));
}
__device__ __forceinline__ void gl2lds16(const void* g, void* l) {
    __builtin_amdgcn_global_load_lds(
        (const __attribute__((address_space(1))) unsigned int*)g,
        (__attribute__((address_space(3))) unsigned int*)l, 16, 0, 0);
}

// ---------------- LayerNorm over C=256, one row per 256-thread block ----------------
template<typename TO>
__global__ __launch_bounds__(256) void ln_kernel(const float* __restrict__ in,
        const float* __restrict__ g, const float* __restrict__ b,
        TO* __restrict__ out) {
    const int r = blockIdx.x;
    const int t = threadIdx.x;
    const size_t base = (size_t)r * Cc;
    float val = in[base + t];
    float s = val, s2 = val * val;
    #pragma unroll
    for (int o = 32; o > 0; o >>= 1) { s += __shfl_down(s, o); s2 += __shfl_down(s2, o); }
    __shared__ float ps[4], ps2[4];
    if ((t & 63) == 0) { ps[t >> 6] = s; ps2[t >> 6] = s2; }
    __syncthreads();
    const float ts  = ps[0] + ps[1] + ps[2] + ps[3];
    const float ts2 = ps2[0] + ps2[1] + ps2[2] + ps2[3];
    const float mean = ts * (1.0f / Cc);
    const float var  = ts2 * (1.0f / Cc) - mean * mean;
    const float rstd = rsqrtf(var + 1e-5f);
    const float v = (val - mean) * rstd * g[t] + b[t];
    if constexpr (std::is_same<TO, float>::value) out[base + t] = v;
    else out[base + t] = f2bf(v);
}

// ---------------- Weight prep: f32 [K,N] -> bf16 [N,K] (transposed), QKV fused+padded ----
// Also transposes depthwise weights [1024][9] -> [9][1024] f32 for coalesced loads.
__global__ __launch_bounds__(256) void prep_weights(
        const float* __restrict__ w_v, const float* __restrict__ b_v,
        const float* __restrict__ w_off, const float* __restrict__ b_off,
        const float* __restrict__ w_attn, const float* __restrict__ b_attn,
        const float* __restrict__ w_out, const float* __restrict__ w1,
        const float* __restrict__ w2, const float* __restrict__ w_dw,
        unsigned short* __restrict__ qkvT, float* __restrict__ qkvB,
        unsigned short* __restrict__ woutT, unsigned short* __restrict__ w1T,
        unsigned short* __restrict__ w2T, float* __restrict__ wdwT) {
    const int blk = blockIdx.x;
    const int t = threadIdx.x;
    if (blk < NQKV) {                      // qkvT row n, K=256
        const int n = blk;
        float val = 0.0f;
        if (n < 256)       val = w_v[t * 256 + n];
        else if (n < 400)  val = w_off[t * 144 + (n - 256)];
        else if (n < 472)  val = w_attn[t * 72 + (n - 400)];
        qkvT[n * 256 + t] = f2bf(val);
        if (t == 0) {
            float bv = 0.0f;
            if (n < 256)      bv = b_v[n];
            else if (n < 400) bv = b_off[n - 256];
            else if (n < 472) bv = b_attn[n - 400];
            qkvB[n] = bv;
        }
    } else if (blk < NQKV + 256) {         // woutT row n, K=256
        const int n = blk - NQKV;
        woutT[n * 256 + t] = f2bf(w_out[t * 256 + n]);
    } else if (blk < NQKV + 256 + 1024) {  // w1T row n, K=256
        const int n = blk - (NQKV + 256);
        w1T[n * 256 + t] = f2bf(w1[t * 1024 + n]);
    } else if (blk < NQKV + 256 + 1024 + 256) { // w2T row n, K=1024
        const int n = blk - (NQKV + 256 + 1024);
        #pragma unroll
        for (int k = t; k < 1024; k += 256)
            w2T[n * 1024 + k] = f2bf(w2[k * 256 + n]);
    } else {                               // wdwT row j (9 rows)
        const int j = blk - (NQKV + 256 + 1024 + 256);
        #pragma unroll
        for (int c = t; c < HIDDEN; c += 256)
            wdwT[j * HIDDEN + c] = w_dw[c * 9 + j];
    }
}

// ---------------- bf16 MFMA GEMM: Out[M,N] = A[M,K] @ BT[N,K]^T + bias ----------------
// Tile 128 x BN, BK=64, 256 threads (4 waves, 2x2 wave grid), 16x16x32 bf16 MFMA.
// LDS layout: [rows][64] bf16 (128 B / row) with G4 XOR swizzle byte^=((row&7)<<4),
// realized as linear global_load_lds dest + inverse-swizzled global source (rule #21).
template<int BN, bool GELU, bool RESID, typename TO>
__global__ __launch_bounds__(256) void mfma_gemm(
        const unsigned short* __restrict__ A,   // [M,K] bf16
        const unsigned short* __restrict__ BT,  // [N,K] bf16
        const float* __restrict__ bias,         // [N]
        const float* __restrict__ resid,        // [M,N] f32 (if RESID)
        TO* __restrict__ Out,                   // [M,N]
        int N, int K) {
    constexpr int NFR = BN / 32;                // B fragments per wave (128->4, 64->2)
    __shared__ unsigned short As[128 * 64];
    __shared__ unsigned short Bs[BN * 64];
    const int t = threadIdx.x;
    const int w = t >> 6;
    const int l = t & 63;
    const int row0 = blockIdx.y * 128;
    const int col0 = blockIdx.x * BN;
    const int wr = (w >> 1) * 64;               // wave row offset in tile
    const int wc = (w & 1) * (BN / 2);          // wave col offset in tile

    // staging geometry: chunk = 8 rows x 64 cols (1024 B); lane l -> row c*8+l/8,
    // 16B slot (l%8); source slot is XOR-swizzled so LDS holds swizzled layout.
    const int srow = l >> 3;
    const int selem = ((l & 7) ^ srow) * 8;     // element offset of this lane's 16B

    f32x4 acc[4][NFR] = {};

    for (int k0 = 0; k0 < K; k0 += 64) {
        #pragma unroll
        for (int i = 0; i < 4; ++i) {           // A tile: 16 chunks, 4 per wave
            const int c = w + i * 4;
            const int row = c * 8 + srow;
            gl2lds16(A + (size_t)(row0 + row) * K + k0 + selem, As + c * 512);
        }
        #pragma unroll
        for (int i = 0; i < NFR; ++i) {         // B tile: BN/8 chunks
            const int c = w + i * 4;
            const int row = c * 8 + srow;
            gl2lds16(BT + (size_t)(col0 + row) * K + k0 + selem, Bs + c * 512);
        }
        asm volatile("s_waitcnt vmcnt(0)" ::: "memory");
        __syncthreads();
        #pragma unroll
        for (int ks = 0; ks < 2; ++ks) {
            const int kb = ks * 64 + (l >> 4) * 16;   // byte offset within 128B row
            bf16x8 af[4], bfr[NFR];
            #pragma unroll
            for (int mi = 0; mi < 4; ++mi) {
                const int row = wr + mi * 16 + (l & 15);
                af[mi] = *(const bf16x8*)((const char*)As + row * 128 + (kb ^ ((row & 7) << 4)));
            }
            #pragma unroll
            for (int ni = 0; ni < NFR; ++ni) {
                const int row = wc + ni * 16 + (l & 15);
                bfr[ni] = *(const bf16x8*)((const char*)Bs + row * 128 + (kb ^ ((row & 7) << 4)));
            }
            #pragma unroll
            for (int mi = 0; mi < 4; ++mi)
                #pragma unroll
                for (int ni = 0; ni < NFR; ++ni)
                    acc[mi][ni] = __builtin_amdgcn_mfma_f32_16x16x32_bf16(
                        af[mi], bfr[ni], acc[mi][ni], 0, 0, 0);
        }
        __syncthreads();
    }

    // epilogue: C/D layout col=l&15, row=(l>>4)*4+reg (guide §3, m89-verified)
    const int lrow = (l >> 4) * 4;
    const int lcol = l & 15;
    #pragma unroll
    for (int ni = 0; ni < NFR; ++ni) {
        const int col = col0 + wc + ni * 16 + lcol;
        const float bb = bias[col];
        #pragma unroll
        for (int mi = 0; mi < 4; ++mi) {
            #pragma unroll
            for (int r = 0; r < 4; ++r) {
                const int row = row0 + wr + mi * 16 + lrow + r;
                float v = acc[mi][ni][r] + bb;
                if constexpr (GELU) v = gelu_exact(v);
                const size_t o = (size_t)row * N + col;
                if constexpr (RESID) v += resid[o];
                if constexpr (std::is_same<TO, float>::value) Out[o] = v;
                else Out[o] = f2bf(v);
            }
        }
    }
}

// ---------------- Deformable sampling + softmax + aggregation (bf16 in/out) ----------------
// F = fused QKV buffer [M, 512]: cols 0-255 v, 256-399 offsets, 400-471 attn logits.
__global__ __launch_bounds__(256) void sample_kernel(const unsigned short* __restrict__ F,
        const float* __restrict__ refp, unsigned short* __restrict__ agg) {
    const int m = blockIdx.x;
    const int b = m / NPIX;
    const int pix = m - b * NPIX;
    const int t = threadIdx.x;
    __shared__ int   s_i0[72], s_i1[72], s_i2[72], s_i3[72];
    __shared__ float s_w0[72], s_w1[72], s_w2[72], s_w3[72];
    __shared__ float s_lg[72];
    if (t < 72) {
        const int head = t / 9, k = t - head * 9;
        const size_t fb = (size_t)m * NQKV;
        const float ox = bf2f(F[fb + 256 + head * 18 + k * 2 + 0]);
        const float oy = bf2f(F[fb + 256 + head * 18 + k * 2 + 1]);
        const float rx = refp[((size_t)pix * KPT + k) * 2 + 0];
        const float ry = refp[((size_t)pix * KPT + k) * 2 + 1];
        const float cx = (rx + ox + 1.0f) * 0.5f * (Wc - 1);
        const float cy = (ry + oy + 1.0f) * 0.5f * (Hc - 1);
        const float fx = floorf(cx), fy = floorf(cy);
        const float wx = cx - fx, wy = cy - fy;
        const int x0 = min(max((int)fx, 0), Wc - 1);
        const int x1 = min(max((int)fx + 1, 0), Wc - 1);
        const int y0 = min(max((int)fy, 0), Hc - 1);
        const int y1 = min(max((int)fy + 1, 0), Hc - 1);
        s_i0[t] = y0 * Wc + x0; s_i1[t] = y0 * Wc + x1;
        s_i2[t] = y1 * Wc + x0; s_i3[t] = y1 * Wc + x1;
        s_w0[t] = (1.0f - wy) * (1.0f - wx); s_w1[t] = (1.0f - wy) * wx;
        s_w2[t] = wy * (1.0f - wx);          s_w3[t] = wy * wx;
        s_lg[t] = bf2f(F[fb + 400 + t]);
    }
    __syncthreads();
    if (t < 72) {
        const int head = t / 9;
        float mx = -1e30f;
        #pragma unroll
        for (int k = 0; k < 9; ++k) mx = fmaxf(mx, s_lg[head * 9 + k]);
        float sm = 0.0f;
        #pragma unroll
        for (int k = 0; k < 9; ++k) sm += __expf(s_lg[head * 9 + k] - mx);
        const float a = __expf(s_lg[t] - mx) / sm;
        s_w0[t] *= a; s_w1[t] *= a; s_w2[t] *= a; s_w3[t] *= a;
    }
    __syncthreads();
    const int head = t >> 5, d = t & 31;
    const unsigned short* vb = F + (size_t)b * NPIX * NQKV + head * HD + d;
    float acc = 0.0f;
    #pragma unroll
    for (int k = 0; k < 9; ++k) {
        const int hk = head * 9 + k;
        acc += bf2f(vb[(size_t)s_i0[hk] * NQKV]) * s_w0[hk]
             + bf2f(vb[(size_t)s_i1[hk] * NQKV]) * s_w1[hk]
             + bf2f(vb[(size_t)s_i2[hk] * NQKV]) * s_w2[hk]
             + bf2f(vb[(size_t)s_i3[hk] * NQKV]) * s_w3[hk];
    }
    agg[(size_t)m * Cc + t] = f2bf(acc);
}

// ---------------- Depthwise 3x3 conv (circular W, zero H) + GELU, bf16 in/out ----------------
// Quad-of-pixels per block: each block computes 4 consecutive x positions for all 1024
// channels; thread t owns channels [4t,4t+4) for all 4 outputs. Loads 3 rows x 6 cols
// (18 independent ushort4 per thread) -> 2x less L2 traffic + 4x ILP vs 1-pixel blocks.
__global__ __launch_bounds__(256) void dwconv_kernel(const unsigned short* __restrict__ h,
        const float* __restrict__ wdwT, const float* __restrict__ bdw,
        unsigned short* __restrict__ h2) {
    constexpr int NQ = 4;                     // x-positions per block
    constexpr int nblk = Mrows / NQ;          // 4096
    const int bid = blockIdx.x;
    const int qi = (bid & 7) * (nblk / 8) + (bid >> 3);   // XCD-chunked swizzle (4096 % 8 == 0)
    const int m0 = qi * NQ;                   // quad never crosses a row (Wc % NQ == 0)
    const int b = m0 / NPIX;
    const int pix0 = m0 - b * NPIX;
    const int y = pix0 / Wc, x0 = pix0 - y * Wc;
    const int t = threadIdx.x;
    const int c0 = t * 4;

    float wreg[9][4];
    #pragma unroll
    for (int j = 0; j < 9; ++j) {
        const float4 wv = *reinterpret_cast<const float4*>(wdwT + j * HIDDEN + c0);
        wreg[j][0] = wv.x; wreg[j][1] = wv.y; wreg[j][2] = wv.z; wreg[j][3] = wv.w;
    }

    float acc[NQ][4] = {};
    #pragma unroll
    for (int dy = -1; dy <= 1; ++dy) {
        const int yy = y + dy;
        if (yy < 0 || yy >= Hc) continue;     // zero pad along height (block-uniform branch)
        const size_t rowbase = ((size_t)b * NPIX + (size_t)yy * Wc) * HIDDEN + c0;
        #pragma unroll
        for (int j = 0; j < NQ + 2; ++j) {    // columns x0-1 .. x0+NQ (circular)
            const int xx = (x0 + j - 1 + Wc) & (Wc - 1);
            const ushort4 hv = *reinterpret_cast<const ushort4*>(h + rowbase + (size_t)xx * HIDDEN);
            const float f0 = bf2f(hv.x), f1 = bf2f(hv.y), f2 = bf2f(hv.z), f3 = bf2f(hv.w);
            #pragma unroll
            for (int q = 0; q < NQ; ++q) {
                if (q >= j - 2 && q <= j) {   // folds to constants after unroll
                    const int wj = (dy + 1) * 3 + (j - q);
                    acc[q][0] += f0 * wreg[wj][0];
                    acc[q][1] += f1 * wreg[wj][1];
                    acc[q][2] += f2 * wreg[wj][2];
                    acc[q][3] += f3 * wreg[wj][3];
                }
            }
        }
    }
    const float4 bb = *reinterpret_cast<const float4*>(bdw + c0);
    #pragma unroll
    for (int q = 0; q < NQ; ++q) {
        ushort4 o;
        o.x = f2bf(gelu_exact(acc[q][0] + bb.x));
        o.y = f2bf(gelu_exact(acc[q][1] + bb.y));
        o.z = f2bf(gelu_exact(acc[q][2] + bb.z));
        o.w = f2bf(gelu_exact(acc[q][3] + bb.w));
        *reinterpret_cast<ushort4*>(h2 + (size_t)(m0 + q) * HIDDEN + c0) = o;
    }
}

extern "C" void kernel_launch(void* const* d_in, const int* in_sizes, int n_in,
                              void* d_out, int out_size, void* d_ws, size_t ws_size,
                              hipStream_t stream) {
    const float* x      = (const float*)d_in[0];
    const float* refp   = (const float*)d_in[1];
    const float* ln1_g  = (const float*)d_in[2];
    const float* ln1_b  = (const float*)d_in[3];
    const float* w_v    = (const float*)d_in[4];
    const float* b_v    = (const float*)d_in[5];
    const float* w_off  = (const float*)d_in[6];
    const float* b_off  = (const float*)d_in[7];
    const float* w_attn = (const float*)d_in[8];
    const float* b_attn = (const float*)d_in[9];
    const float* w_out  = (const float*)d_in[10];
    const float* b_out  = (const float*)d_in[11];
    const float* ln2_g  = (const float*)d_in[12];
    const float* ln2_b  = (const float*)d_in[13];
    const float* w1     = (const float*)d_in[14];
    const float* b1     = (const float*)d_in[15];
    const float* w_dw   = (const float*)d_in[16];
    const float* b_dw   = (const float*)d_in[17];
    const float* w2     = (const float*)d_in[18];
    const float* b2     = (const float*)d_in[19];
    float* out = (float*)d_out;

    // Workspace layout (bytes); lifetimes make the overlaps safe:
    //  [0,  8M): xn -> agg -> y          (bf16 [M,256], sequential reuse)
    //  [8, 24M): F fused qkv (bf16 [M,512]) — dead after sample_kernel
    //  [8, 40M): h (bf16 [M,1024])       — written after F is dead
    //  [40,72M): h2 (bf16 [M,1024])
    //  [72M,..): transposed bf16 weights + wdwT + fused qkv bias
    char* wsb = (char*)d_ws;
    unsigned short* xnR = (unsigned short*)(wsb);
    unsigned short* F   = (unsigned short*)(wsb + (8ull  << 20));
    unsigned short* h   = (unsigned short*)(wsb + (8ull  << 20));
    unsigned short* h2  = (unsigned short*)(wsb + (40ull << 20));
    size_t woff = 72ull << 20;
    unsigned short* qkvT = (unsigned short*)(wsb + woff); woff += (size_t)NQKV * 256 * 2;
    unsigned short* woutT= (unsigned short*)(wsb + woff); woff += 256 * 256 * 2;
    unsigned short* w1T  = (unsigned short*)(wsb + woff); woff += 1024 * 256 * 2;
    unsigned short* w2T  = (unsigned short*)(wsb + woff); woff += 256 * 1024 * 2;
    float*          wdwT = (float*)(wsb + woff);          woff += 9 * 1024 * 4;
    float*          qkvB = (float*)(wsb + woff);

    // 0. weight transpose/convert (independent of activations)
    prep_weights<<<NQKV + 256 + 1024 + 256 + 9, 256, 0, stream>>>(
        w_v, b_v, w_off, b_off, w_attn, b_attn, w_out, w1, w2, w_dw,
        qkvT, qkvB, woutT, w1T, w2T, wdwT);
    // 1. LN1 -> xn (bf16)
    ln_kernel<unsigned short><<<Mrows, 256, 0, stream>>>(x, ln1_g, ln1_b, xnR);
    // 2. fused QKV GEMM: F = xn @ [w_v|w_off|w_attn] + bias  (bf16 out)
    mfma_gemm<128, false, false, unsigned short><<<dim3(NQKV / 128, Mrows / 128), 256, 0, stream>>>(
        xnR, qkvT, qkvB, nullptr, F, NQKV, 256);
    // 3. deformable sampling + softmax + aggregation -> agg (reuses xn region)
    sample_kernel<<<Mrows, 256, 0, stream>>>(F, refp, xnR);
    // 4. x2 = x + agg @ w_out + b_out -> d_out (f32)
    mfma_gemm<64, false, true, float><<<dim3(256 / 64, Mrows / 128), 256, 0, stream>>>(
        xnR, woutT, b_out, x, out, 256, 256);
    // 5. LN2 -> y (bf16, reuses xn region)
    ln_kernel<unsigned short><<<Mrows, 256, 0, stream>>>(out, ln2_g, ln2_b, xnR);
    // 6. h = gelu(y @ w1 + b1) (bf16)
    mfma_gemm<128, true, false, unsigned short><<<dim3(1024 / 128, Mrows / 128), 256, 0, stream>>>(
        xnR, w1T, b1, nullptr, h, 1024, 256);
    // 7. depthwise conv + gelu -> h2 (bf16)
    dwconv_kernel<<<Mrows / 4, 256, 0, stream>>>(h, wdwT, b_dw, h2);
    // 8. out = x2 + h2 @ w2 + b2 (f32, in-place residual)
    mfma_gemm<64, false, true, float><<<dim3(256 / 64, Mrows / 128), 256, 0, stream>>>(
        h2, w2T, b2, out, out, 256, 1024);
}